// Round 2
// baseline (709.618 us; speedup 1.0000x reference)
//
#include <hip/hip_runtime.h>
#include <cstdint>
#include <cstddef>

// Problem constants
#define BB 8
#define SS 1024
#define DDIM 512
#define HH 8
#define BS 8192   // BB*SS
#define HD 4096   // HH*DDIM

typedef __attribute__((ext_vector_type(4))) float f32x4;
typedef __attribute__((ext_vector_type(8))) short bf16x8;    // 8 bf16 (4 VGPRs) — MFMA A/B frag
typedef __attribute__((ext_vector_type(4))) unsigned short u16x4;

// ---- helpers -------------------------------------------------------------

__device__ __forceinline__ unsigned short f2bf(float f) {
  union { float f; unsigned int u; } x; x.f = f;
  unsigned int r = x.u + 0x7fffu + ((x.u >> 16) & 1u);   // RNE
  return (unsigned short)(r >> 16);
}

// async global->LDS, 16B per lane. LDS dest is wave-uniform base + lane*16.
__device__ __forceinline__ void gload16(const void* g, void* l) {
  __builtin_amdgcn_global_load_lds(
      (const __attribute__((address_space(1))) unsigned int*)g,
      (__attribute__((address_space(3))) unsigned int*)l, 16, 0, 0);
}

// ---- conversion / transpose kernels -------------------------------------

__global__ void k_convert(const float* __restrict__ in, unsigned short* __restrict__ out, int n4) {
  int i = blockIdx.x * blockDim.x + threadIdx.x;
  if (i < n4) {
    float4 v = ((const float4*)in)[i];
    u16x4 o;
    o[0] = f2bf(v.x); o[1] = f2bf(v.y); o[2] = f2bf(v.z); o[3] = f2bf(v.w);
    ((u16x4*)out)[i] = o;
  }
}

// in: f32 [z][R][C] -> out: bf16 [z][C][R]
__global__ void k_transpose_f2b(const float* __restrict__ in, unsigned short* __restrict__ out,
                                int R, int C) {
  __shared__ unsigned short tile[64][65];
  const int z = blockIdx.z;
  const int r0 = blockIdx.x << 6, c0 = blockIdx.y << 6;
  const float* ip = in + (size_t)z * R * C;
  unsigned short* op = out + (size_t)z * R * C;
  const int t = threadIdx.x;
#pragma unroll
  for (int i = 0; i < 16; ++i) {
    int idx = t + (i << 8); int r = idx >> 6, c = idx & 63;
    tile[r][c] = f2bf(ip[(size_t)(r0 + r) * C + (c0 + c)]);
  }
  __syncthreads();
#pragma unroll
  for (int i = 0; i < 16; ++i) {
    int idx = t + (i << 8); int c = idx >> 6, r = idx & 63;
    op[(size_t)(c0 + c) * R + (r0 + r)] = tile[r][c];
  }
}

// in: bf16 [z][R][C] -> out: bf16 [z][C][R]
__global__ void k_transpose_b2b(const unsigned short* __restrict__ in,
                                unsigned short* __restrict__ out, int R, int C) {
  __shared__ unsigned short tile[64][65];
  const int z = blockIdx.z;
  const int r0 = blockIdx.x << 6, c0 = blockIdx.y << 6;
  const unsigned short* ip = in + (size_t)z * R * C;
  unsigned short* op = out + (size_t)z * R * C;
  const int t = threadIdx.x;
#pragma unroll
  for (int i = 0; i < 16; ++i) {
    int idx = t + (i << 8); int r = idx >> 6, c = idx & 63;
    tile[r][c] = ip[(size_t)(r0 + r) * C + (c0 + c)];
  }
  __syncthreads();
#pragma unroll
  for (int i = 0; i < 16; ++i) {
    int idx = t + (i << 8); int c = idx >> 6, r = idx & 63;
    op[(size_t)(c0 + c) * R + (r0 + r)] = tile[r][c];
  }
}

// ---- GEMM core: 128x128 tile, BK=64, 4 waves, gload_lds + XOR swizzle ----
// A: [M][K] bf16 row-major (row stride A_RS bytes). B: [N][K] bf16 (row stride B_RS).
// LDS tiles [128 rows][64 k] bf16 = 128B rows; swizzle: byte ^= (row&7)<<4.
template<int A_RS, int B_RS, int KITERS>
__device__ __forceinline__ void gemm_core(const char* Ag, const char* Bg,
                                          char* As, char* Bs, f32x4 acc[4][4]) {
  const int tid = threadIdx.x;
  const int wave = tid >> 6, lane = tid & 63;
  const int wr = (wave >> 1) << 6, wc = (wave & 1) << 6;
  const int srow = (wave << 3) + (lane >> 3);                       // 0..31
  const int scol = ((lane & 7) << 4) ^ ((lane >> 3) << 4);          // pre-swizzled source col byte

  for (int kb = 0; kb < KITERS; ++kb) {
    __syncthreads();   // previous compute done before overwriting LDS
#pragma unroll
    for (int j = 0; j < 4; ++j) {
      gload16(Ag + (size_t)(j * 32 + srow) * A_RS + (size_t)kb * 128 + scol,
              As + j * 4096 + wave * 1024);
      gload16(Bg + (size_t)(j * 32 + srow) * B_RS + (size_t)kb * 128 + scol,
              Bs + j * 4096 + wave * 1024);
    }
    asm volatile("s_waitcnt vmcnt(0)" ::: "memory");
    __syncthreads();
#pragma unroll
    for (int ks = 0; ks < 2; ++ks) {
      bf16x8 af[4], bfr[4];
      const int kcol = (ks << 6) + ((lane >> 4) << 4);
#pragma unroll
      for (int i = 0; i < 4; ++i) {
        const int ar = wr + (i << 4) + (lane & 15);
        af[i] = *(const bf16x8*)(As + ar * 128 + (kcol ^ ((ar & 7) << 4)));
        const int br = wc + (i << 4) + (lane & 15);
        bfr[i] = *(const bf16x8*)(Bs + br * 128 + (kcol ^ ((br & 7) << 4)));
      }
#pragma unroll
      for (int i = 0; i < 4; ++i)
#pragma unroll
        for (int j = 0; j < 4; ++j)
          acc[i][j] = __builtin_amdgcn_mfma_f32_16x16x32_bf16(af[i], bfr[j], acc[i][j], 0, 0, 0);
    }
  }
}

// ---- QKV projection (phase of nb batches): z = p*8+h ---------------------
__global__ __launch_bounds__(256, 2) void k_gemm_qkv(
    const unsigned short* __restrict__ xbf,
    const unsigned short* __restrict__ wqT, const unsigned short* __restrict__ wkT,
    const unsigned short* __restrict__ wvT,
    const float* __restrict__ bq, const float* __restrict__ bk, const float* __restrict__ bv,
    unsigned short* __restrict__ Qo, unsigned short* __restrict__ Ko,
    unsigned short* __restrict__ Vo, int b0) {
  __shared__ __align__(16) char As[16384], Bs[16384];
  const int z = blockIdx.z;
  const int p = z >> 3, h = z & 7;
  const unsigned short* wT = (p == 0) ? wqT : (p == 1) ? wkT : wvT;
  const float* bias = ((p == 0) ? bq : (p == 1) ? bk : bv) + (h << 9);
  unsigned short* dst = (p == 0) ? Qo : (p == 1) ? Ko : Vo;
  const int m0 = blockIdx.x << 7, n0 = blockIdx.y << 7;   // m0 local to phase
  const char* Ag = (const char*)xbf + ((size_t)(b0 << 10) + m0) * 1024;
  const char* Bg = (const char*)wT + (size_t)h * 524288 + (size_t)n0 * 1024;
  f32x4 acc[4][4] = {};
  gemm_core<1024, 1024, 8>(Ag, Bg, As, Bs, acc);

  const int tid = threadIdx.x, wave = tid >> 6, lane = tid & 63;
  const int wr = (wave >> 1) << 6, wc = (wave & 1) << 6;
#pragma unroll
  for (int j = 0; j < 4; ++j) {
    const int col = n0 + wc + (j << 4) + (lane & 15);
    const float bb = bias[col];
#pragma unroll
    for (int i = 0; i < 4; ++i)
#pragma unroll
      for (int r = 0; r < 4; ++r) {
        const int m = m0 + wr + (i << 4) + ((lane >> 4) << 2) + r;   // local row
        const int lb = m >> 10, s = m & 1023;
        dst[((size_t)((lb * HH + h) * SS + s) << 9) + col] = f2bf(acc[i][j][r] + bb);
      }
  }
}

// ---- output projection: out[m][e] = concat[m][:]*Wo[:][e] + bo[e] (f32) ---
__global__ __launch_bounds__(256, 2) void k_gemm_out(
    const unsigned short* __restrict__ concat, const unsigned short* __restrict__ woT,
    const float* __restrict__ bo, float* __restrict__ out) {
  __shared__ __align__(16) char As[16384], Bs[16384];
  const int m0 = blockIdx.x << 7, n0 = blockIdx.y << 7;
  const char* Ag = (const char*)concat + (size_t)m0 * 8192;
  const char* Bg = (const char*)woT + (size_t)n0 * 8192;
  f32x4 acc[4][4] = {};
  gemm_core<8192, 8192, 64>(Ag, Bg, As, Bs, acc);

  const int tid = threadIdx.x, wave = tid >> 6, lane = tid & 63;
  const int wr = (wave >> 1) << 6, wc = (wave & 1) << 6;
#pragma unroll
  for (int j = 0; j < 4; ++j) {
    const int col = n0 + wc + (j << 4) + (lane & 15);
    const float bb = bo[col];
#pragma unroll
    for (int i = 0; i < 4; ++i)
#pragma unroll
      for (int r = 0; r < 4; ++r) {
        const int m = m0 + wr + (i << 4) + ((lane >> 4) << 2) + r;
        out[(size_t)m * DDIM + col] = acc[i][j][r] + bb;
      }
  }
}

// ---- flash attention: qtile=32, kv-tile=64, 8 waves, static 143.7KB LDS --
// LDS: K [64][512] 64KB | VT [512][64] 64KB | S f32 [32][64] 8KB |
//      P bf16 [32][64] 4KB | m/l/fac [32] each
__global__ __launch_bounds__(512, 1) void k_attn(
    const unsigned short* __restrict__ Qg, const unsigned short* __restrict__ Kg,
    const unsigned short* __restrict__ VTg, unsigned short* __restrict__ Og,
    int b0, int bhMask, int bhShift) {
  __shared__ __align__(16) char smem[143744];
  char* Ksm = smem;                         // 65536
  char* Vsm = smem + 65536;                 // 65536
  float* Ssm = (float*)(smem + 131072);     // 8192
  char* Psm = smem + 139264;                // 4096
  float* msm = (float*)(smem + 143360);
  float* lsm = (float*)(smem + 143488);
  float* fsm = (float*)(smem + 143616);

  const int tid = threadIdx.x, wave = tid >> 6, lane = tid & 63;
  const int qt = blockIdx.x >> bhShift;
  const int bh = blockIdx.x & bhMask;       // local (lb*8 + h); XCD-friendly decode
  const int q0 = qt << 5;
  const char* Qb = (const char*)Qg + (size_t)bh * (SS * DDIM * 2);
  const char* Kb = (const char*)Kg + (size_t)bh * (SS * DDIM * 2);
  const char* Vb = (const char*)VTg + (size_t)bh * (SS * DDIM * 2);   // [D][S]

  if (tid < 32) { msm[tid] = -1e30f; lsm[tid] = 0.0f; }

  // stage Q tile (32 x 512) into Ksm; row&7 == wave matches source XOR
#pragma unroll
  for (int j = 0; j < 4; ++j) {
    const int row = (j << 3) + wave;
    gload16(Qb + (size_t)(q0 + row) * 1024 + ((lane << 4) ^ (wave << 4)),
            Ksm + row * 1024);
  }
  asm volatile("s_waitcnt vmcnt(0)" ::: "memory");
  __syncthreads();

  // Q fragments -> registers. wave: qi = wave>>2 (q-frag), ni = wave&3 (kv-frag)
  const int qi = wave >> 2, ni = wave & 3;
  bf16x8 qf[16];
  {
    const int qrow = (qi << 4) + (lane & 15);
    const int qswz = (qrow & 7) << 4;
#pragma unroll
    for (int ks = 0; ks < 16; ++ks)
      qf[ks] = *(const bf16x8*)(Ksm + qrow * 1024 + (((ks << 6) + ((lane >> 4) << 4)) ^ qswz));
  }
  __syncthreads();

  f32x4 accO[2][4] = {};
  const float scale = 0.044194173824159216f;   // 1/sqrt(512)

  for (int kt = 0; kt < 16; ++kt) {
    const int kv0 = kt << 6;
#pragma unroll
    for (int j = 0; j < 8; ++j) {
      const int row = (j << 3) + wave;
      gload16(Kb + (size_t)(kv0 + row) * 1024 + ((lane << 4) ^ (wave << 4)),
              Ksm + row * 1024);
    }
#pragma unroll
    for (int j = 0; j < 8; ++j) {
      const int drow = (j << 6) + (wave << 3) + (lane >> 3);   // drow&7 == lane>>3
      gload16(Vb + (size_t)drow * 2048 + (size_t)(kv0 << 1) +
                  (((lane & 7) << 4) ^ ((lane >> 3) << 4)),
              Vsm + (j << 13) + (wave << 10));
    }
    asm volatile("s_waitcnt vmcnt(0)" ::: "memory");
    __syncthreads();

    // QK^T: each wave one 16x16 S-fragment
    {
      f32x4 accS = {};
      const int krow = (ni << 4) + (lane & 15);
      const int kswz = (krow & 7) << 4;
#pragma unroll
      for (int ks = 0; ks < 16; ++ks) {
        const bf16x8 kf = *(const bf16x8*)(Ksm + krow * 1024 +
            (((ks << 6) + ((lane >> 4) << 4)) ^ kswz));
        accS = __builtin_amdgcn_mfma_f32_16x16x32_bf16(qf[ks], kf, accS, 0, 0, 0);
      }
      const int srow = (qi << 4) + ((lane >> 4) << 2);
      const int scol = (ni << 4) + (lane & 15);
#pragma unroll
      for (int r = 0; r < 4; ++r) Ssm[(srow + r) * 64 + scol] = accS[r];
    }
    __syncthreads();

    // online softmax: 16 lanes per row, 4 cols each
    {
      const int row = tid >> 4, c0 = (tid & 15) << 2;
      float sv[4];
#pragma unroll
      for (int c = 0; c < 4; ++c) sv[c] = Ssm[row * 64 + c0 + c] * scale;
      float mx = fmaxf(fmaxf(sv[0], sv[1]), fmaxf(sv[2], sv[3]));
      mx = fmaxf(mx, __shfl_xor(mx, 1));
      mx = fmaxf(mx, __shfl_xor(mx, 2));
      mx = fmaxf(mx, __shfl_xor(mx, 4));
      mx = fmaxf(mx, __shfl_xor(mx, 8));
      const float mold = msm[row];                 // read before lane0 writes (lockstep)
      const float mnew = fmaxf(mold, mx);
      const float fac = __expf(mold - mnew);
      float ls = 0.0f;
      u16x4 pv;
#pragma unroll
      for (int c = 0; c < 4; ++c) {
        const float p = __expf(sv[c] - mnew);
        ls += p;
        pv[c] = f2bf(p);
      }
      ls += __shfl_xor(ls, 1);
      ls += __shfl_xor(ls, 2);
      ls += __shfl_xor(ls, 4);
      ls += __shfl_xor(ls, 8);
      if ((tid & 15) == 0) {
        msm[row] = mnew;
        lsm[row] = lsm[row] * fac + ls;
        fsm[row] = fac;
      }
      *(u16x4*)(Psm + row * 128 + ((c0 << 1) ^ ((row & 7) << 4))) = pv;
    }
    __syncthreads();

    // rescale O, then PV: wave owns d-slice [wave*64, wave*64+64)
    {
      float facs[2][4];
      const int rbase = (lane >> 4) << 2;
#pragma unroll
      for (int i = 0; i < 2; ++i)
#pragma unroll
        for (int r = 0; r < 4; ++r) facs[i][r] = fsm[(i << 4) + rbase + r];
#pragma unroll
      for (int i = 0; i < 2; ++i)
#pragma unroll
        for (int j = 0; j < 4; ++j)
#pragma unroll
          for (int r = 0; r < 4; ++r) accO[i][j][r] *= facs[i][r];
#pragma unroll
      for (int ks = 0; ks < 2; ++ks) {
        bf16x8 pf[2], vf[4];
        const int kcol = (ks << 6) + ((lane >> 4) << 4);
#pragma unroll
        for (int i = 0; i < 2; ++i) {
          const int pr = (i << 4) + (lane & 15);
          pf[i] = *(const bf16x8*)(Psm + pr * 128 + (kcol ^ ((pr & 7) << 4)));
        }
#pragma unroll
        for (int j = 0; j < 4; ++j) {
          const int vr = (wave << 6) + (j << 4) + (lane & 15);
          vf[j] = *(const bf16x8*)(Vsm + vr * 128 + (kcol ^ ((vr & 7) << 4)));
        }
#pragma unroll
        for (int i = 0; i < 2; ++i)
#pragma unroll
          for (int j = 0; j < 4; ++j)
            accO[i][j] = __builtin_amdgcn_mfma_f32_16x16x32_bf16(pf[i], vf[j], accO[i][j], 0, 0, 0);
      }
    }
    __syncthreads();   // protect Ksm/Vsm/Psm/Ssm before next tile
  }

  // epilogue: O /= l, write concat [b][s][h*512+d] bf16
  {
    const int b = b0 + (bh >> 3), h = bh & 7;
    const int rbase = (lane >> 4) << 2;
    float linv[2][4];
#pragma unroll
    for (int i = 0; i < 2; ++i)
#pragma unroll
      for (int r = 0; r < 4; ++r) linv[i][r] = 1.0f / lsm[(i << 4) + rbase + r];
#pragma unroll
    for (int i = 0; i < 2; ++i)
#pragma unroll
      for (int j = 0; j < 4; ++j) {
        const int col = (wave << 6) + (j << 4) + (lane & 15);
#pragma unroll
        for (int r = 0; r < 4; ++r) {
          const int s = q0 + (i << 4) + rbase + r;
          Og[((size_t)((b << 10) + s)) * HD + (h << 9) + col] = f2bf(accO[i][j][r] * linv[i][r]);
        }
      }
  }
}

// ---- host launch ---------------------------------------------------------

extern "C" void kernel_launch(void* const* d_in, const int* in_sizes, int n_in,
                              void* d_out, int out_size, void* d_ws, size_t ws_size,
                              hipStream_t stream) {
  const float* x  = (const float*)d_in[0];
  const float* Wq = (const float*)d_in[1];
  const float* bq = (const float*)d_in[2];
  const float* Wk = (const float*)d_in[3];
  const float* bk = (const float*)d_in[4];
  const float* Wv = (const float*)d_in[5];
  const float* bv = (const float*)d_in[6];
  const float* Wo = (const float*)d_in[7];
  const float* bo = (const float*)d_in[8];
  float* out = (float*)d_out;
  char* ws = (char*)d_ws;

  // static region: xbf 8MB | wqT/wkT/wvT 4MB each | woT 4MB | concat 64MB
  unsigned short* xbf = (unsigned short*)(ws);
  unsigned short* wqT = (unsigned short*)(ws + 8388608);
  unsigned short* wkT = (unsigned short*)(ws + 12582912);
  unsigned short* wvT = (unsigned short*)(ws + 16777216);
  unsigned short* woT = (unsigned short*)(ws + 20971520);
  unsigned short* Cw  = (unsigned short*)(ws + 25165824);     // 64MB
  const size_t pbase = 25165824ull + 67108864ull;             // 92274688

  // phase buffers: Q/K/V/VT, each nb*8MB. nb=1 -> 120MB total, nb=2 -> 152MB.
  int nb = 1;
  if (ws_size >= pbase + 4ull * 2ull * 8388608ull) nb = 2;
  const size_t pb = (size_t)nb * 8388608ull;
  unsigned short* Qp  = (unsigned short*)(ws + pbase);
  unsigned short* Kp  = (unsigned short*)(ws + pbase + pb);
  unsigned short* Vp  = (unsigned short*)(ws + pbase + 2 * pb);
  unsigned short* VTp = (unsigned short*)(ws + pbase + 3 * pb);

  // 1) convert x to bf16; transpose weights to [N][K] bf16
  k_convert<<<4096, 256, 0, stream>>>(x, xbf, BS * DDIM / 4);
  k_transpose_f2b<<<dim3(8, 8, 8), 256, 0, stream>>>(Wq, wqT, 512, 512);
  k_transpose_f2b<<<dim3(8, 8, 8), 256, 0, stream>>>(Wk, wkT, 512, 512);
  k_transpose_f2b<<<dim3(8, 8, 8), 256, 0, stream>>>(Wv, wvT, 512, 512);
  k_transpose_f2b<<<dim3(64, 8, 1), 256, 0, stream>>>(Wo, woT, 4096, 512);

  // 2) phased QKV -> transpose V -> attention
  const int bhShift = (nb == 2) ? 4 : 3;
  const int bhMask = (8 * nb) - 1;
  for (int b0 = 0; b0 < BB; b0 += nb) {
    k_gemm_qkv<<<dim3(8 * nb, 4, 24), 256, 0, stream>>>(xbf, wqT, wkT, wvT,
                                                        bq, bk, bv, Qp, Kp, Vp, b0);
    k_transpose_b2b<<<dim3(16, 8, 8 * nb), 256, 0, stream>>>(Vp, VTp, SS, DDIM);
    k_attn<<<dim3(32 << bhShift), 512, 0, stream>>>(Qp, Kp, VTp, Cw, b0, bhMask, bhShift);
  }

  // 3) output projection (f32 out)
  k_gemm_out<<<dim3(64, 4), 256, 0, stream>>>(Cw, woT, bo, out);
}

// Round 3
// 689.455 us; speedup vs baseline: 1.0292x; 1.0292x over previous
//
#include <hip/hip_runtime.h>
#include <cstdint>
#include <cstddef>

// Problem constants
#define BB 8
#define SS 1024
#define DDIM 512
#define HH 8
#define BS 8192   // BB*SS
#define HD 4096   // HH*DDIM

typedef __attribute__((ext_vector_type(4))) float f32x4;
typedef __attribute__((ext_vector_type(8))) short bf16x8;    // 8 bf16 (4 VGPRs) — MFMA A/B frag
typedef __attribute__((ext_vector_type(4))) unsigned short u16x4;

// ---- helpers -------------------------------------------------------------

__device__ __forceinline__ unsigned short f2bf(float f) {
  union { float f; unsigned int u; } x; x.f = f;
  unsigned int r = x.u + 0x7fffu + ((x.u >> 16) & 1u);   // RNE
  return (unsigned short)(r >> 16);
}

// async global->LDS, 16B per lane. LDS dest is wave-uniform base + lane*16.
__device__ __forceinline__ void gload16(const void* g, void* l) {
  __builtin_amdgcn_global_load_lds(
      (const __attribute__((address_space(1))) unsigned int*)g,
      (__attribute__((address_space(3))) unsigned int*)l, 16, 0, 0);
}

// raw barrier + producer-side LDS drain (does NOT drain vmcnt -> staging stays in flight)
#define BAR_LGKM() do { asm volatile("s_waitcnt lgkmcnt(0)" ::: "memory"); \
                        __builtin_amdgcn_s_barrier(); } while (0)
// full drain barrier (staging complete)
#define BAR_ALL()  do { asm volatile("s_waitcnt vmcnt(0) lgkmcnt(0)" ::: "memory"); \
                        __builtin_amdgcn_s_barrier(); } while (0)

// ---- conversion / transpose kernels -------------------------------------

__global__ void k_convert(const float* __restrict__ in, unsigned short* __restrict__ out, int n4) {
  int i = blockIdx.x * blockDim.x + threadIdx.x;
  if (i < n4) {
    float4 v = ((const float4*)in)[i];
    u16x4 o;
    o[0] = f2bf(v.x); o[1] = f2bf(v.y); o[2] = f2bf(v.z); o[3] = f2bf(v.w);
    ((u16x4*)out)[i] = o;
  }
}

// in: f32 [z][R][C] -> out: bf16 [z][C][R]
__global__ void k_transpose_f2b(const float* __restrict__ in, unsigned short* __restrict__ out,
                                int R, int C) {
  __shared__ unsigned short tile[64][65];
  const int z = blockIdx.z;
  const int r0 = blockIdx.x << 6, c0 = blockIdx.y << 6;
  const float* ip = in + (size_t)z * R * C;
  unsigned short* op = out + (size_t)z * R * C;
  const int t = threadIdx.x;
#pragma unroll
  for (int i = 0; i < 16; ++i) {
    int idx = t + (i << 8); int r = idx >> 6, c = idx & 63;
    tile[r][c] = f2bf(ip[(size_t)(r0 + r) * C + (c0 + c)]);
  }
  __syncthreads();
#pragma unroll
  for (int i = 0; i < 16; ++i) {
    int idx = t + (i << 8); int c = idx >> 6, r = idx & 63;
    op[(size_t)(c0 + c) * R + (r0 + r)] = tile[r][c];
  }
}

// in: bf16 [z][R][C] -> out: bf16 [z][C][R]
__global__ void k_transpose_b2b(const unsigned short* __restrict__ in,
                                unsigned short* __restrict__ out, int R, int C) {
  __shared__ unsigned short tile[64][65];
  const int z = blockIdx.z;
  const int r0 = blockIdx.x << 6, c0 = blockIdx.y << 6;
  const unsigned short* ip = in + (size_t)z * R * C;
  unsigned short* op = out + (size_t)z * R * C;
  const int t = threadIdx.x;
#pragma unroll
  for (int i = 0; i < 16; ++i) {
    int idx = t + (i << 8); int r = idx >> 6, c = idx & 63;
    tile[r][c] = ip[(size_t)(r0 + r) * C + (c0 + c)];
  }
  __syncthreads();
#pragma unroll
  for (int i = 0; i < 16; ++i) {
    int idx = t + (i << 8); int c = idx >> 6, r = idx & 63;
    op[(size_t)(c0 + c) * R + (r0 + r)] = tile[r][c];
  }
}

// ---- GEMM core: 128x128 tile, BK=64, 4 waves, gload_lds + XOR swizzle ----
template<int A_RS, int B_RS, int KITERS>
__device__ __forceinline__ void gemm_core(const char* Ag, const char* Bg,
                                          char* As, char* Bs, f32x4 acc[4][4]) {
  const int tid = threadIdx.x;
  const int wave = tid >> 6, lane = tid & 63;
  const int wr = (wave >> 1) << 6, wc = (wave & 1) << 6;
  const int srow = (wave << 3) + (lane >> 3);                       // 0..31
  const int scol = ((lane & 7) << 4) ^ ((lane >> 3) << 4);          // pre-swizzled source col byte

  for (int kb = 0; kb < KITERS; ++kb) {
    __syncthreads();
#pragma unroll
    for (int j = 0; j < 4; ++j) {
      gload16(Ag + (size_t)(j * 32 + srow) * A_RS + (size_t)kb * 128 + scol,
              As + j * 4096 + wave * 1024);
      gload16(Bg + (size_t)(j * 32 + srow) * B_RS + (size_t)kb * 128 + scol,
              Bs + j * 4096 + wave * 1024);
    }
    asm volatile("s_waitcnt vmcnt(0)" ::: "memory");
    __syncthreads();
#pragma unroll
    for (int ks = 0; ks < 2; ++ks) {
      bf16x8 af[4], bfr[4];
      const int kcol = (ks << 6) + ((lane >> 4) << 4);
#pragma unroll
      for (int i = 0; i < 4; ++i) {
        const int ar = wr + (i << 4) + (lane & 15);
        af[i] = *(const bf16x8*)(As + ar * 128 + (kcol ^ ((ar & 7) << 4)));
        const int br = wc + (i << 4) + (lane & 15);
        bfr[i] = *(const bf16x8*)(Bs + br * 128 + (kcol ^ ((br & 7) << 4)));
      }
#pragma unroll
      for (int i = 0; i < 4; ++i)
#pragma unroll
        for (int j = 0; j < 4; ++j)
          acc[i][j] = __builtin_amdgcn_mfma_f32_16x16x32_bf16(af[i], bfr[j], acc[i][j], 0, 0, 0);
    }
  }
}

// ---- QKV projection (phase of nb batches): z = p*8+h ---------------------
__global__ __launch_bounds__(256, 2) void k_gemm_qkv(
    const unsigned short* __restrict__ xbf,
    const unsigned short* __restrict__ wqT, const unsigned short* __restrict__ wkT,
    const unsigned short* __restrict__ wvT,
    const float* __restrict__ bq, const float* __restrict__ bk, const float* __restrict__ bv,
    unsigned short* __restrict__ Qo, unsigned short* __restrict__ Ko,
    unsigned short* __restrict__ Vo, int b0) {
  __shared__ __align__(16) char As[16384], Bs[16384];
  const int z = blockIdx.z;
  const int p = z >> 3, h = z & 7;
  const unsigned short* wT = (p == 0) ? wqT : (p == 1) ? wkT : wvT;
  const float* bias = ((p == 0) ? bq : (p == 1) ? bk : bv) + (h << 9);
  unsigned short* dst = (p == 0) ? Qo : (p == 1) ? Ko : Vo;
  const int m0 = blockIdx.x << 7, n0 = blockIdx.y << 7;   // m0 local to phase
  const char* Ag = (const char*)xbf + ((size_t)(b0 << 10) + m0) * 1024;
  const char* Bg = (const char*)wT + (size_t)h * 524288 + (size_t)n0 * 1024;
  f32x4 acc[4][4] = {};
  gemm_core<1024, 1024, 8>(Ag, Bg, As, Bs, acc);

  const int tid = threadIdx.x, wave = tid >> 6, lane = tid & 63;
  const int wr = (wave >> 1) << 6, wc = (wave & 1) << 6;
#pragma unroll
  for (int j = 0; j < 4; ++j) {
    const int col = n0 + wc + (j << 4) + (lane & 15);
    const float bb = bias[col];
#pragma unroll
    for (int i = 0; i < 4; ++i)
#pragma unroll
      for (int r = 0; r < 4; ++r) {
        const int m = m0 + wr + (i << 4) + ((lane >> 4) << 2) + r;   // local row
        const int lb = m >> 10, s = m & 1023;
        dst[((size_t)((lb * HH + h) * SS + s) << 9) + col] = f2bf(acc[i][j][r] + bb);
      }
  }
}

// ---- output projection: out[m][e] = concat[m][:]*Wo[:][e] + bo[e] (f32) ---
__global__ __launch_bounds__(256, 2) void k_gemm_out(
    const unsigned short* __restrict__ concat, const unsigned short* __restrict__ woT,
    const float* __restrict__ bo, float* __restrict__ out) {
  __shared__ __align__(16) char As[16384], Bs[16384];
  const int m0 = blockIdx.x << 7, n0 = blockIdx.y << 7;
  const char* Ag = (const char*)concat + (size_t)m0 * 8192;
  const char* Bg = (const char*)woT + (size_t)n0 * 8192;
  f32x4 acc[4][4] = {};
  gemm_core<8192, 8192, 64>(Ag, Bg, As, Bs, acc);

  const int tid = threadIdx.x, wave = tid >> 6, lane = tid & 63;
  const int wr = (wave >> 1) << 6, wc = (wave & 1) << 6;
#pragma unroll
  for (int j = 0; j < 4; ++j) {
    const int col = n0 + wc + (j << 4) + (lane & 15);
    const float bb = bo[col];
#pragma unroll
    for (int i = 0; i < 4; ++i)
#pragma unroll
      for (int r = 0; r < 4; ++r) {
        const int m = m0 + wr + (i << 4) + ((lane >> 4) << 2) + r;
        out[(size_t)m * DDIM + col] = acc[i][j][r] + bb;
      }
  }
}

// ---- flash attention v3: qtile=32, kv=32, 4 waves, 73KB LDS, 2 blocks/CU --
// LDS: K [32][512] 32KB | VT [512][32] 32KB | S f32 [32][36] 4.5KB |
//      P bf16 [32 rows x 80B] 2.5KB | m/l/f [32] each.
// Schedule: stage(kt) -> BAR_ALL -> QK^T -> S -> BAR_LGKM -> issue K(kt+1) ->
//           softmax -> BAR_LGKM -> read P,V,f -> BAR_LGKM -> issue VT(kt+1) ->
//           rescale+PV-MFMA -> loop. Raw barriers keep staging in flight.
__global__ __launch_bounds__(256, 2) void k_attn(
    const unsigned short* __restrict__ Qg, const unsigned short* __restrict__ Kg,
    const unsigned short* __restrict__ VTg, unsigned short* __restrict__ Og,
    int b0, int bhMask, int bhShift) {
  __shared__ __align__(16) char smem[73088];
  char* Ksm = smem;                          // 32768
  char* Vsm = smem + 32768;                  // 32768
  float* Ssm = (float*)(smem + 65536);       // 32*36*4 = 4608
  char* Psm = smem + 70144;                  // 32*80 = 2560
  float* msm = (float*)(smem + 72704);
  float* lsm = (float*)(smem + 72832);
  float* fsm = (float*)(smem + 72960);

  const int tid = threadIdx.x, wave = tid >> 6, lane = tid & 63;
  const int qt = blockIdx.x >> bhShift;
  const int bh = blockIdx.x & bhMask;        // low bits -> same-XCD blocks share (b,h)
  const int q0 = qt << 5;
  const char* Qb = (const char*)Qg + (size_t)bh * (SS * DDIM * 2);
  const char* Kb = (const char*)Kg + (size_t)bh * (SS * DDIM * 2);
  const char* Vb = (const char*)VTg + (size_t)bh * (SS * DDIM * 2);   // [D][S]

  const int qi = wave >> 1, ni = wave & 1;   // QK^T frag coords

  if (tid < 32) { msm[tid] = -1e30f; lsm[tid] = 0.0f; }

  // ---- prologue: Q tile (32x512) -> Ksm -> qf regs ----
#pragma unroll
  for (int j = 0; j < 8; ++j) {
    const int row = (j << 2) + wave;
    gload16(Qb + (size_t)(q0 + row) * 1024 + ((lane << 4) ^ ((row & 7) << 4)),
            Ksm + row * 1024);
  }
  BAR_ALL();
  bf16x8 qf[16];
  {
    const int qrow = (qi << 4) + (lane & 15);
    const int qswz = (qrow & 7) << 4;
    const int kg = (lane >> 4) << 4;
#pragma unroll
    for (int ks = 0; ks < 16; ++ks)
      qf[ks] = *(const bf16x8*)(Ksm + qrow * 1024 + (((ks << 6) + kg) ^ qswz));
  }
  BAR_LGKM();   // Q reads done before K staging overwrites

  // ---- stage helpers ----
#define STAGE_K(KV0)                                                           \
  {                                                                            \
    _Pragma("unroll")                                                          \
    for (int j = 0; j < 8; ++j) {                                              \
      const int row = (j << 2) + wave;                                         \
      gload16(Kb + (size_t)((KV0) + row) * 1024 + ((lane << 4) ^ ((row & 7) << 4)), \
              Ksm + row * 1024);                                               \
    }                                                                          \
  }
#define STAGE_V(KV0)                                                           \
  {                                                                            \
    _Pragma("unroll")                                                          \
    for (int j = 0; j < 8; ++j) {                                              \
      const int idx = (j << 2) + wave;                                         \
      const int dr = (idx << 4) + (lane >> 2);                                 \
      gload16(Vb + (size_t)dr * 2048 + (size_t)((KV0) << 1) +                  \
                  (((lane & 3) << 4) ^ (((lane >> 2) & 3) << 4)),              \
              Vsm + idx * 1024);                                               \
    }                                                                          \
  }

  STAGE_K(0);
  STAGE_V(0);

  f32x4 accO[2][8] = {};
  const float scale = 0.044194173824159216f;   // 1/sqrt(512)

  for (int kt = 0; kt < 32; ++kt) {
    const int kvn = (kt + 1) << 5;
    BAR_ALL();   // staged K/VT ready; prior-phase LDS ops visible

    // ---- QK^T: one 16x16 S-frag per wave, K=512 over 16 MFMA (2 chains) ----
    f32x4 a0 = {}, a1 = {};
    {
      const int krow = (ni << 4) + (lane & 15);
      const char* kb2 = Ksm + krow * 1024;
      const int ksz = (krow & 7) << 4;
      const int kg = (lane >> 4) << 4;
      __builtin_amdgcn_s_setprio(1);
#pragma unroll
      for (int ks = 0; ks < 16; ks += 2) {
        const bf16x8 k0 = *(const bf16x8*)(kb2 + (((ks << 6) + kg) ^ ksz));
        const bf16x8 k1 = *(const bf16x8*)(kb2 + ((((ks + 1) << 6) + kg) ^ ksz));
        a0 = __builtin_amdgcn_mfma_f32_16x16x32_bf16(qf[ks], k0, a0, 0, 0, 0);
        a1 = __builtin_amdgcn_mfma_f32_16x16x32_bf16(qf[ks + 1], k1, a1, 0, 0, 0);
      }
      __builtin_amdgcn_s_setprio(0);
    }
    {
      const int srow = (qi << 4) + ((lane >> 4) << 2);
      const int scol = (ni << 4) + (lane & 15);
#pragma unroll
      for (int r = 0; r < 4; ++r) Ssm[(srow + r) * 36 + scol] = a0[r] + a1[r];
    }
    BAR_LGKM();   // S visible; all K-reads done

    if (kt != 31) STAGE_K(kvn);   // K(kt+1) hides under softmax+PV

    // ---- online softmax: 8 lanes/row, vectorized f32x4 ----
    {
      const int row = tid >> 3, c8 = tid & 7;
      f32x4 sv = *(const f32x4*)(Ssm + row * 36 + (c8 << 2));
#pragma unroll
      for (int c = 0; c < 4; ++c) sv[c] *= scale;
      float mx = fmaxf(fmaxf(sv[0], sv[1]), fmaxf(sv[2], sv[3]));
      mx = fmaxf(mx, __shfl_xor(mx, 1));
      mx = fmaxf(mx, __shfl_xor(mx, 2));
      mx = fmaxf(mx, __shfl_xor(mx, 4));
      const float mold = msm[row];               // in-wave lockstep: read precedes write
      const float mnew = fmaxf(mold, mx);
      const float fac = __expf(mold - mnew);
      float ls = 0.0f;
      u16x4 pv;
#pragma unroll
      for (int c = 0; c < 4; ++c) {
        const float p = __expf(sv[c] - mnew);
        ls += p;
        pv[c] = f2bf(p);
      }
      ls += __shfl_xor(ls, 1);
      ls += __shfl_xor(ls, 2);
      ls += __shfl_xor(ls, 4);
      if ((tid & 7) == 0) {
        msm[row] = mnew;
        lsm[row] = lsm[row] * fac + ls;
        fsm[row] = fac;
      }
      *(u16x4*)(Psm + row * 80 + (c8 << 3)) = pv;
    }
    BAR_LGKM();   // P, f visible

    // ---- PV: wave owns d-slice [wave*128, +128) ----
    {
      float facs[2][4];
      bf16x8 pf[2], vf[8];
      const int rb = (lane >> 4) << 2;
      const int kg = (lane >> 4) << 4;
#pragma unroll
      for (int i = 0; i < 2; ++i) {
#pragma unroll
        for (int r = 0; r < 4; ++r) facs[i][r] = fsm[(i << 4) + rb + r];
        const int pr = (i << 4) + (lane & 15);
        pf[i] = *(const bf16x8*)(Psm + pr * 80 + kg);
      }
#pragma unroll
      for (int j = 0; j < 8; ++j) {
        const int vr = (wave << 7) + (j << 4) + (lane & 15);
        vf[j] = *(const bf16x8*)(Vsm + vr * 64 + (kg ^ ((vr & 3) << 4)));
      }
      BAR_LGKM();   // all P/V reads done

      if (kt != 31) STAGE_V(kvn);   // VT(kt+1) hides under PV MFMA

#pragma unroll
      for (int i = 0; i < 2; ++i)
#pragma unroll
        for (int j = 0; j < 8; ++j)
#pragma unroll
          for (int r = 0; r < 4; ++r) accO[i][j][r] *= facs[i][r];
      __builtin_amdgcn_s_setprio(1);
#pragma unroll
      for (int i = 0; i < 2; ++i)
#pragma unroll
        for (int j = 0; j < 8; ++j)
          accO[i][j] = __builtin_amdgcn_mfma_f32_16x16x32_bf16(pf[i], vf[j], accO[i][j], 0, 0, 0);
      __builtin_amdgcn_s_setprio(0);
    }
  }

  // ---- epilogue: O /= l, write concat [b][s][h*512+d] bf16 ----
  {
    const int b = b0 + (bh >> 3), h = bh & 7;
    const int rb = (lane >> 4) << 2;
    float linv[2][4];
#pragma unroll
    for (int i = 0; i < 2; ++i)
#pragma unroll
      for (int r = 0; r < 4; ++r) linv[i][r] = 1.0f / lsm[(i << 4) + rb + r];
#pragma unroll
    for (int i = 0; i < 2; ++i)
#pragma unroll
      for (int j = 0; j < 8; ++j) {
        const int col = (wave << 7) + (j << 4) + (lane & 15);
#pragma unroll
        for (int r = 0; r < 4; ++r) {
          const int s = q0 + (i << 4) + rb + r;
          Og[((size_t)((b << 10) + s)) * HD + (h << 9) + col] = f2bf(accO[i][j][r] * linv[i][r]);
        }
      }
  }
#undef STAGE_K
#undef STAGE_V
}

// ---- host launch ---------------------------------------------------------

extern "C" void kernel_launch(void* const* d_in, const int* in_sizes, int n_in,
                              void* d_out, int out_size, void* d_ws, size_t ws_size,
                              hipStream_t stream) {
  const float* x  = (const float*)d_in[0];
  const float* Wq = (const float*)d_in[1];
  const float* bq = (const float*)d_in[2];
  const float* Wk = (const float*)d_in[3];
  const float* bk = (const float*)d_in[4];
  const float* Wv = (const float*)d_in[5];
  const float* bv = (const float*)d_in[6];
  const float* Wo = (const float*)d_in[7];
  const float* bo = (const float*)d_in[8];
  float* out = (float*)d_out;
  char* ws = (char*)d_ws;

  // static region: xbf 8MB | wqT/wkT/wvT 4MB each | woT 4MB | concat 64MB
  unsigned short* xbf = (unsigned short*)(ws);
  unsigned short* wqT = (unsigned short*)(ws + 8388608);
  unsigned short* wkT = (unsigned short*)(ws + 12582912);
  unsigned short* wvT = (unsigned short*)(ws + 16777216);
  unsigned short* woT = (unsigned short*)(ws + 20971520);
  unsigned short* Cw  = (unsigned short*)(ws + 25165824);     // 64MB
  const size_t pbase = 25165824ull + 67108864ull;             // 92274688

  // phase buffers Q/K/V/VT, each nb*8MB. nb=1:120MB, nb=2:152MB, nb=8:348MB.
  int nb = 1;
  if (ws_size >= pbase + 4ull * 8ull * 8388608ull) nb = 8;
  else if (ws_size >= pbase + 4ull * 2ull * 8388608ull) nb = 2;
  const size_t pb = (size_t)nb * 8388608ull;
  unsigned short* Qp  = (unsigned short*)(ws + pbase);
  unsigned short* Kp  = (unsigned short*)(ws + pbase + pb);
  unsigned short* Vp  = (unsigned short*)(ws + pbase + 2 * pb);
  unsigned short* VTp = (unsigned short*)(ws + pbase + 3 * pb);

  // 1) convert x to bf16; transpose weights to [N][K] bf16
  k_convert<<<4096, 256, 0, stream>>>(x, xbf, BS * DDIM / 4);
  k_transpose_f2b<<<dim3(8, 8, 8), 256, 0, stream>>>(Wq, wqT, 512, 512);
  k_transpose_f2b<<<dim3(8, 8, 8), 256, 0, stream>>>(Wk, wkT, 512, 512);
  k_transpose_f2b<<<dim3(8, 8, 8), 256, 0, stream>>>(Wv, wvT, 512, 512);
  k_transpose_f2b<<<dim3(64, 8, 1), 256, 0, stream>>>(Wo, woT, 4096, 512);

  // 2) phased QKV -> transpose V -> attention (qtile=32 -> 32 qtiles)
  const int bhShift = (nb == 8) ? 6 : (nb == 2) ? 4 : 3;
  const int bhMask = (8 * nb) - 1;
  for (int b0 = 0; b0 < BB; b0 += nb) {
    k_gemm_qkv<<<dim3(8 * nb, 4, 24), 256, 0, stream>>>(xbf, wqT, wkT, wvT,
                                                        bq, bk, bv, Qp, Kp, Vp, b0);
    k_transpose_b2b<<<dim3(16, 8, 8 * nb), 256, 0, stream>>>(Vp, VTp, SS, DDIM);
    k_attn<<<dim3(32 << bhShift), 256, 0, stream>>>(Qp, Kp, VTp, Cw, b0, bhMask, bhShift);
  }

  // 3) output projection (f32 out)
  k_gemm_out<<<dim3(64, 4), 256, 0, stream>>>(Cw, woT, bo, out);
}